// Round 10
// baseline (80.192 us; speedup 1.0000x reference)
//
#include <hip/hip_runtime.h>
#include <stdint.h>

// Problem dims
#define NB   4096   // batch rows (M)
#define KD   2048   // IN + S   (K)
#define ND   4096   // 4*S      (N, reordered: n -> gate=(n>>4)&3, s=(n>>6)*16+(n&15))
#define SD   1024   // state size

// GEMM tile (256x256, 8 waves = 2M x 4N, register-double-buffered 2-phase)
#define BM   256
#define BN   256
#define BK   64
#define NKT  (KD / BK)   // 32 K-tiles

using f32x4  = __attribute__((ext_vector_type(4))) float;
using bf16x8 = __attribute__((ext_vector_type(8))) short;

typedef const __attribute__((address_space(1))) uint32_t* gas_u32;
typedef __attribute__((address_space(3))) uint32_t* las_u32;

__device__ __forceinline__ unsigned short f2bf(float f) {
    union { float f; uint32_t u; } c; c.f = f;
    uint32_t u = c.u;
    uint32_t r = (u + 0x7fffu + ((u >> 16) & 1u)) >> 16;  // RNE
    return (unsigned short)r;
}

__device__ __forceinline__ void async_load16(const void* gsrc, void* ldst) {
    __builtin_amdgcn_global_load_lds((gas_u32)gsrc, (las_u32)ldst, 16, 0, 0);
}

__device__ __forceinline__ float frcp(float x) { return __builtin_amdgcn_rcpf(x); }
__device__ __forceinline__ float sigm(float x) { return frcp(1.f + __expf(-x)); }
__device__ __forceinline__ float tanh_fast(float x) {
    return 1.f - 2.f * frcp(1.f + __expf(2.f * x));   // inf-safe
}

// ---------------------------------------------------------------------------
// Pack: fp32 -> bf16, X=[input|old_h]; W rows reordered so GEMM column
// n maps to weights row  gate*SD + (n>>6)*16 + (n&15),  gate=(n>>4)&3.
// ---------------------------------------------------------------------------
__global__ void pack_kernel(const float* __restrict__ input,
                            const float* __restrict__ old_h,
                            const float* __restrict__ weights,
                            const float* __restrict__ bias,
                            unsigned short* __restrict__ Xb,
                            unsigned short* __restrict__ Wb,
                            float* __restrict__ biasR) {
    const int XCH = NB * (KD / 4);
    const int WCH = ND * (KD / 4);
    const int BCH = ND / 4;
    const int total = XCH + WCH + BCH;
    for (int c = blockIdx.x * blockDim.x + threadIdx.x; c < total;
         c += gridDim.x * blockDim.x) {
        if (c < XCH) {
            int b  = c >> 9;
            int k  = (c & 511) << 2;
            const float* src = (k < 1024) ? (input + (size_t)b * 1024 + k)
                                          : (old_h + (size_t)b * 1024 + (k - 1024));
            float4 v = *reinterpret_cast<const float4*>(src);
            ushort4 o;
            o.x = f2bf(v.x); o.y = f2bf(v.y); o.z = f2bf(v.z); o.w = f2bf(v.w);
            *reinterpret_cast<ushort4*>(Xb + (size_t)b * KD + k) = o;
        } else if (c < XCH + WCH) {
            int cc = c - XCH;
            int n  = cc >> 9;
            int k  = (cc & 511) << 2;
            int srow = ((n >> 4) & 3) * SD + ((n >> 6) * 16 + (n & 15));
            float4 v = *reinterpret_cast<const float4*>(weights + (size_t)srow * KD + k);
            ushort4 o;
            o.x = f2bf(v.x); o.y = f2bf(v.y); o.z = f2bf(v.z); o.w = f2bf(v.w);
            *reinterpret_cast<ushort4*>(Wb + (size_t)n * KD + k) = o;
        } else {
            int n4 = (c - XCH - WCH) << 2;
            #pragma unroll
            for (int t = 0; t < 4; ++t) {
                int n = n4 + t;
                biasR[n] = bias[((n >> 4) & 3) * SD + ((n >> 6) * 16 + (n & 15))];
            }
        }
    }
}

// ---------------------------------------------------------------------------
// 256x256 GEMM + fused LSTM epilogue; 2 phases/K-tile, register-double-
// buffered fragments: phase p's ds_reads fill the set consumed in phase p+1,
// while phase p's 32 MFMAs consume the OTHER set. No RAW between a phase's
// reads and its MFMAs; disjoint reg sets (no WAR). Block-wide LDS drain
// (~857 cyc, 96 KB) hides fully under the 1242-cyc MFMA window.
//   p0(t): reads (t,h1)->setB [12]; MFMA32 (t,h0) on setA;
//          lgkm0 (reads drained, issued a phase ago) + vmcnt(0) (gates
//          stage(t+1), issued 1.5 phases ago) + BARRIER b0
//   p1(t): stage(t+2)->buf[t%2] [8 loads]; reads (t+1,h0)->setA [12, from
//          buf[(t+1)%2], gated at b0]; MFMA32 (t,h1) on setB; BARRIER b1
// Region ledger: buf[t%2] last read = (t,h1) reads in p0(t), drained by
// lgkm0 before b0 -> stage(t+2) after b0 is safe (all waves). buf[(t+1)%2]
// last written = stage(t+1), per-wave drained by vmcnt(0) before b0 ->
// reads after b0 safe. In-flight (t+1,h0) reads cross b1; nothing writes
// their region until stage(t+3) in p1(t+1), after b0(t+1)'s lgkm0. b1
// needs no waitcnt. vmcnt(0) at b0(t): outstanding = stage(t+1) only
// (stage(t+2) issues after b0). Prologue: stage t0+t1 (16), vmcnt(8)
// -> t0 landed, t1 in flight = loop invariant; preload (t0,h0)->setA.
// ---------------------------------------------------------------------------
#define SEG(DB, AB, HALF) (((((DB) * 2 + (AB)) * 2) + (HALF)) * 8192)

#define SBAR   __builtin_amdgcn_s_barrier()
#define SFENCE __builtin_amdgcn_sched_barrier(0)
#define SGB(M, N)  __builtin_amdgcn_sched_group_barrier((M), (N), 0)
#define ASM_LGKM0  asm volatile("s_waitcnt lgkmcnt(0)" ::: "memory")
#define ASM_VMCNT0 asm volatile("s_waitcnt vmcnt(0)" ::: "memory")
#define ASM_VMCNT8 asm volatile("s_waitcnt vmcnt(8)" ::: "memory")

__launch_bounds__(512, 2)
__global__ void lstm_gemm(const unsigned short* __restrict__ Xb,
                          const unsigned short* __restrict__ Wb,
                          const float* __restrict__ biasR,
                          const float* __restrict__ old_cell,
                          float* __restrict__ new_h,
                          float* __restrict__ new_cell) {
    __shared__ unsigned short lds[65536];   // 128 KiB

    const int tid  = threadIdx.x;
    const int lane = tid & 63;
    const int wid  = tid >> 6;       // 0..7
    const int wm   = wid >> 2;       // 0..1  (M half owner)
    const int wn   = wid & 3;        // 0..3  (N quarter owner)
    const int l15  = lane & 15;
    const int krow = lane >> 4;      // 0..3

    // XCD-aware bijective swizzle (256 blocks, 8 XCDs)
    const int wg    = blockIdx.x;
    const int swz   = (wg & 7) * 32 + (wg >> 3);
    const int mblk  = swz >> 4;
    const int nblk  = swz & 15;
    const int rbase = mblk * BM;
    const int nbase = nblk * BN;

    // staging per-thread constants: half-tile = 128 rows x 64 cols = 1024 chunks
    const int c0 = tid, c1 = tid + 512;
    const int srow0 = c0 >> 3, sk0 = ((c0 & 7) ^ (srow0 & 7)) * 8;
    const int srow1 = c1 >> 3, sk1 = ((c1 & 7) ^ (srow1 & 7)) * 8;

    f32x4  acc[8][4] = {};
    bf16x8 aA[8], aB[8];   // A frags: wave's 128-row band x one 32-col k-half
    bf16x8 bA[4], bB[4];   // B frags: wave's 64-col panel x one 32-col k-half

#define STAGE(PTR, TB, KT, DB, AB, HALF) do {                                   \
        async_load16((PTR) + (size_t)((TB) + (HALF) * 128 + srow0) * KD +       \
                         (KT) * BK + sk0,                                       \
                     lds + SEG(DB, AB, HALF) + c0 * 8);                         \
        async_load16((PTR) + (size_t)((TB) + (HALF) * 128 + srow1) * KD +       \
                         (KT) * BK + sk1,                                       \
                     lds + SEG(DB, AB, HALF) + c1 * 8);                         \
    } while (0)

    // 8 ds_read_b128: A frags (full 128-row band of wave wm), k-half KK
#define LOAD_AH(SET, DB, KK) do {                                               \
        const unsigned short* base_ = lds + SEG(DB, 0, 0) + wm * 8192;          \
        _Pragma("unroll") for (int i_ = 0; i_ < 8; ++i_) {                      \
            int r_ = i_ * 16 + l15;                                             \
            int s_ = (KK) * 4 + krow;                                           \
            SET[i_] = *reinterpret_cast<const bf16x8*>(                         \
                base_ + r_ * 64 + ((s_ ^ (r_ & 7)) * 8));                       \
        }                                                                       \
    } while (0)

    // 4 ds_read_b128: B frags (wave's 64-col panel), k-half KK
#define LOAD_BH(SET, DB, KK) do {                                               \
        const unsigned short* base_ = lds + SEG(DB, 1, 0) + (wn >> 1) * 8192;   \
        _Pragma("unroll") for (int j_ = 0; j_ < 4; ++j_) {                      \
            int r_ = (wn & 1) * 64 + j_ * 16 + l15;                             \
            int s_ = (KK) * 4 + krow;                                           \
            SET[j_] = *reinterpret_cast<const bf16x8*>(                         \
                base_ + r_ * 64 + ((s_ ^ (r_ & 7)) * 8));                       \
        }                                                                       \
    } while (0)

    // 32 MFMA: 8 m-subtiles x 4 j, one k-half (consumes resident reg set)
#define MMA32(ASET, BSET) do {                                                  \
        _Pragma("unroll") for (int i_ = 0; i_ < 8; ++i_)                        \
        _Pragma("unroll") for (int j_ = 0; j_ < 4; ++j_)                        \
            acc[i_][j_] = __builtin_amdgcn_mfma_f32_16x16x32_bf16(              \
                ASET[i_], BSET[j_], acc[i_][j_], 0, 0, 0);                      \
    } while (0)

    // ---- prologue: stage tiles 0,1 (FIFO); vmcnt(8)=t0 landed; preload ----
    STAGE(Wb, nbase, 0, 0, 1, 0);
    STAGE(Wb, nbase, 0, 0, 1, 1);
    STAGE(Xb, rbase, 0, 0, 0, 0);
    STAGE(Xb, rbase, 0, 0, 0, 1);
    STAGE(Wb, nbase, 1, 1, 1, 0);
    STAGE(Wb, nbase, 1, 1, 1, 1);
    STAGE(Xb, rbase, 1, 1, 0, 0);
    STAGE(Xb, rbase, 1, 1, 0, 1);
    ASM_VMCNT8;
    SBAR; SFENCE;
    LOAD_AH(aA, 0, 0);
    LOAD_BH(bA, 0, 0);

    // ---- main loop: 2 phases per K-tile ----
#define KBODY(TT, BUF) do {                                                     \
        const int kt2_ = ((TT) + 2) & (NKT - 1);                                \
        /* p0: reads (t,h1)->setB; MFMA32 (t,h0) on setA */                     \
        LOAD_AH(aB, BUF, 1);                                                    \
        LOAD_BH(bB, BUF, 1);                                                    \
        MMA32(aA, bA);                                                          \
        SGB(0x100, 12); SGB(0x8, 32);                                           \
        ASM_LGKM0; ASM_VMCNT0; SBAR; SFENCE;                                    \
        /* p1: stage(t+2)->BUF; reads (t+1,h0)->setA; MFMA32 (t,h1) on setB */  \
        STAGE(Xb, rbase, kt2_, BUF, 0, 0);                                      \
        STAGE(Xb, rbase, kt2_, BUF, 0, 1);                                      \
        STAGE(Wb, nbase, kt2_, BUF, 1, 0);                                      \
        STAGE(Wb, nbase, kt2_, BUF, 1, 1);                                      \
        LOAD_AH(aA, (BUF) ^ 1, 0);                                              \
        LOAD_BH(bA, (BUF) ^ 1, 0);                                              \
        MMA32(aB, bB);                                                          \
        SGB(0x30, 8); SGB(0x100, 12); SGB(0x8, 32);                             \
        SBAR; SFENCE;                                                           \
    } while (0)

    for (int t = 0; t < NKT; t += 2) {
        KBODY(t, 0);
        KBODY(t + 1, 1);
    }

    // ---- fused LSTM epilogue (reg-resident, zero-shuffle) ----
    const int s = (nblk * 4 + wn) * 16 + l15;
    float bg[4];
    #pragma unroll
    for (int jj = 0; jj < 4; ++jj)
        bg[jj] = biasR[nbase + wn * 64 + jj * 16 + l15];

    #pragma unroll
    for (int mi = 0; mi < 8; ++mi) {
        #pragma unroll
        for (int r = 0; r < 4; ++r) {
            const int row = rbase + wm * 128 + mi * 16 + krow * 4 + r;
            float fg = sigm(acc[mi][0][r] + bg[0]);
            float ig = sigm(acc[mi][1][r] + bg[1]);
            float og = sigm(acc[mi][2][r] + bg[2]);
            float gg = tanh_fast(acc[mi][3][r] + bg[3]);
            float oc = old_cell[(size_t)row * SD + s];
            float nc = fmaf(fg, oc, ig * gg);
            float nh = og * tanh_fast(nc);
            new_h[(size_t)row * SD + s]    = nh;
            new_cell[(size_t)row * SD + s] = nc;
        }
    }
}

extern "C" void kernel_launch(void* const* d_in, const int* in_sizes, int n_in,
                              void* d_out, int out_size, void* d_ws, size_t ws_size,
                              hipStream_t stream) {
    const float* input    = (const float*)d_in[0];
    const float* old_h    = (const float*)d_in[1];
    const float* old_cell = (const float*)d_in[2];
    const float* weights  = (const float*)d_in[3];
    const float* bias     = (const float*)d_in[4];

    unsigned short* Xb  = (unsigned short*)d_ws;                             // 16 MiB
    unsigned short* Wb  = (unsigned short*)((char*)d_ws + (size_t)16777216); // 16 MiB
    float*          bR  = (float*)((char*)d_ws + (size_t)33554432);          // 16 KiB

    float* out_h = (float*)d_out;
    float* out_c = out_h + (size_t)NB * SD;

    pack_kernel<<<2048, 256, 0, stream>>>(input, old_h, weights, bias, Xb, Wb, bR);
    lstm_gemm<<<(NB / BM) * (ND / BN), 512, 0, stream>>>(Xb, Wb, bR, old_cell,
                                                         out_h, out_c);
}

// Round 11
// 79.849 us; speedup vs baseline: 1.0043x; 1.0043x over previous
//
#include <hip/hip_runtime.h>
#include <stdint.h>

// Problem dims
#define NB   4096   // batch rows (M)
#define KD   2048   // IN + S   (K)
#define ND   4096   // 4*S      (N, reordered: n -> gate=(n>>4)&3, s=(n>>6)*16+(n&15))
#define SD   1024   // state size

// GEMM tile (256x256, 8 waves = 2M x 4N, 1-barrier free-form K-tile body)
#define BM   256
#define BN   256
#define BK   64
#define NKT  (KD / BK)   // 32 K-tiles

using f32x4  = __attribute__((ext_vector_type(4))) float;
using bf16x8 = __attribute__((ext_vector_type(8))) short;

typedef const __attribute__((address_space(1))) uint32_t* gas_u32;
typedef __attribute__((address_space(3))) uint32_t* las_u32;

__device__ __forceinline__ unsigned short f2bf(float f) {
    union { float f; uint32_t u; } c; c.f = f;
    uint32_t u = c.u;
    uint32_t r = (u + 0x7fffu + ((u >> 16) & 1u)) >> 16;  // RNE
    return (unsigned short)r;
}

__device__ __forceinline__ void async_load16(const void* gsrc, void* ldst) {
    __builtin_amdgcn_global_load_lds((gas_u32)gsrc, (las_u32)ldst, 16, 0, 0);
}

__device__ __forceinline__ float frcp(float x) { return __builtin_amdgcn_rcpf(x); }
__device__ __forceinline__ float sigm(float x) { return frcp(1.f + __expf(-x)); }
__device__ __forceinline__ float tanh_fast(float x) {
    return 1.f - 2.f * frcp(1.f + __expf(2.f * x));   // inf-safe
}

// ---------------------------------------------------------------------------
// Pack: fp32 -> bf16, X=[input|old_h]; W rows reordered so GEMM column
// n maps to weights row  gate*SD + (n>>6)*16 + (n&15),  gate=(n>>4)&3.
// ---------------------------------------------------------------------------
__global__ void pack_kernel(const float* __restrict__ input,
                            const float* __restrict__ old_h,
                            const float* __restrict__ weights,
                            const float* __restrict__ bias,
                            unsigned short* __restrict__ Xb,
                            unsigned short* __restrict__ Wb,
                            float* __restrict__ biasR) {
    const int XCH = NB * (KD / 4);
    const int WCH = ND * (KD / 4);
    const int BCH = ND / 4;
    const int total = XCH + WCH + BCH;
    for (int c = blockIdx.x * blockDim.x + threadIdx.x; c < total;
         c += gridDim.x * blockDim.x) {
        if (c < XCH) {
            int b  = c >> 9;
            int k  = (c & 511) << 2;
            const float* src = (k < 1024) ? (input + (size_t)b * 1024 + k)
                                          : (old_h + (size_t)b * 1024 + (k - 1024));
            float4 v = *reinterpret_cast<const float4*>(src);
            ushort4 o;
            o.x = f2bf(v.x); o.y = f2bf(v.y); o.z = f2bf(v.z); o.w = f2bf(v.w);
            *reinterpret_cast<ushort4*>(Xb + (size_t)b * KD + k) = o;
        } else if (c < XCH + WCH) {
            int cc = c - XCH;
            int n  = cc >> 9;
            int k  = (cc & 511) << 2;
            int srow = ((n >> 4) & 3) * SD + ((n >> 6) * 16 + (n & 15));
            float4 v = *reinterpret_cast<const float4*>(weights + (size_t)srow * KD + k);
            ushort4 o;
            o.x = f2bf(v.x); o.y = f2bf(v.y); o.z = f2bf(v.z); o.w = f2bf(v.w);
            *reinterpret_cast<ushort4*>(Wb + (size_t)n * KD + k) = o;
        } else {
            int n4 = (c - XCH - WCH) << 2;
            #pragma unroll
            for (int t = 0; t < 4; ++t) {
                int n = n4 + t;
                biasR[n] = bias[((n >> 4) & 3) * SD + ((n >> 6) * 16 + (n & 15))];
            }
        }
    }
}

// ---------------------------------------------------------------------------
// 256x256 GEMM + fused LSTM epilogue; ONE barrier + ONE vmcnt per K-tile,
// free-form tile body (R11). Rationale: R4-R10 all re-synced the 8 waves
// 2-4x per K-tile; both waves/SIMD then read together (matrix idle) and
// MFMA together (LDS idle) -> pipes strictly serialized (1270 cyc/phase =
// 620 MFMA + 650 LDS). With one ~2600-cyc body between barriers and no
// manual lgkm waits, waves de-phase: one wave's MFMA burst covers the
// other's LDS drain (compiler emits split lgkmcnt RAW waits only).
// Body u:  vmcnt(0)            // stage(u) landed (issued body u-1, ~2600cyc)
//          s_barrier           // => stage(u) landed BLOCK-WIDE; also fences
//                              //    buf reuse: all tile-(u-1) reads drained
//                              //    (every read feeds a same-tile MFMA)
//          stage(u+1) -> buf[(u+1)&1]   // other buffer; holds dead tile u-1
//          24 ds_reads + 64 MFMAs, free-form (B k0/k1, A mq0; mq1 mid-body)
// Ledger: stage(u+1) after barrier(u-1) => never collides with tile-(u-1)
// reads. Reads(u) after barrier => all waves' stage(u) chunks visible.
// Last body stages tile (32&31)=0 into buf0: dead writes, nothing reads
// buf0 afterwards (epilogue is reg+global only). No final barrier needed.
// ---------------------------------------------------------------------------
#define SEG(DB, AB, HALF) (((((DB) * 2 + (AB)) * 2) + (HALF)) * 8192)

#define SBAR   __builtin_amdgcn_s_barrier()
#define SFENCE __builtin_amdgcn_sched_barrier(0)
#define ASM_VMCNT0 asm volatile("s_waitcnt vmcnt(0)" ::: "memory")

__launch_bounds__(512, 2)
__global__ void lstm_gemm(const unsigned short* __restrict__ Xb,
                          const unsigned short* __restrict__ Wb,
                          const float* __restrict__ biasR,
                          const float* __restrict__ old_cell,
                          float* __restrict__ new_h,
                          float* __restrict__ new_cell) {
    __shared__ unsigned short lds[65536];   // 128 KiB

    const int tid  = threadIdx.x;
    const int lane = tid & 63;
    const int wid  = tid >> 6;       // 0..7
    const int wm   = wid >> 2;       // 0..1  (M half owner)
    const int wn   = wid & 3;        // 0..3  (N quarter owner)
    const int l15  = lane & 15;
    const int krow = lane >> 4;      // 0..3

    // XCD-aware bijective swizzle (256 blocks, 8 XCDs)
    const int wg    = blockIdx.x;
    const int swz   = (wg & 7) * 32 + (wg >> 3);
    const int mblk  = swz >> 4;
    const int nblk  = swz & 15;
    const int rbase = mblk * BM;
    const int nbase = nblk * BN;

    // staging per-thread constants: half-tile = 128 rows x 64 cols = 1024 chunks
    const int c0 = tid, c1 = tid + 512;
    const int srow0 = c0 >> 3, sk0 = ((c0 & 7) ^ (srow0 & 7)) * 8;
    const int srow1 = c1 >> 3, sk1 = ((c1 & 7) ^ (srow1 & 7)) * 8;

    f32x4  acc[8][4] = {};
    bf16x8 a0[4], a1[4];   // A frags, k-half 0/1 of current quadrant (reused mq0->mq1)
    bf16x8 bk0[4], bk1[4]; // B frags, k-half 0/1 (live whole K-tile)

#define STAGE(PTR, TB, KT, DB, AB, HALF) do {                                   \
        async_load16((PTR) + (size_t)((TB) + (HALF) * 128 + srow0) * KD +       \
                         (KT) * BK + sk0,                                       \
                     lds + SEG(DB, AB, HALF) + c0 * 8);                         \
        async_load16((PTR) + (size_t)((TB) + (HALF) * 128 + srow1) * KD +       \
                         (KT) * BK + sk1,                                       \
                     lds + SEG(DB, AB, HALF) + c1 * 8);                         \
    } while (0)

    // 4 ds_read_b128: A fragments for quadrant MQ, k-half KK -> DST
#define LOAD_A4(DST, DB, MQ, KK) do {                                           \
        const unsigned short* base_ = lds + SEG(DB, 0, 0) + wm * 8192;          \
        _Pragma("unroll") for (int i_ = 0; i_ < 4; ++i_) {                      \
            int r_ = (MQ) * 64 + i_ * 16 + l15;                                 \
            int s_ = (KK) * 4 + krow;                                           \
            DST[i_] = *reinterpret_cast<const bf16x8*>(                         \
                base_ + r_ * 64 + ((s_ ^ (r_ & 7)) * 8));                       \
        }                                                                       \
    } while (0)

    // 4 ds_read_b128: B fragments, all 4 j of wave's 64-col panel, k-half KK
#define LOAD_B4(DST, DB, KK) do {                                               \
        const unsigned short* base_ = lds + SEG(DB, 1, 0) + (wn >> 1) * 8192;   \
        _Pragma("unroll") for (int j_ = 0; j_ < 4; ++j_) {                      \
            int r_ = (wn & 1) * 64 + j_ * 16 + l15;                             \
            int s_ = (KK) * 4 + krow;                                           \
            DST[j_] = *reinterpret_cast<const bf16x8*>(                         \
                base_ + r_ * 64 + ((s_ ^ (r_ & 7)) * 8));                       \
        }                                                                       \
    } while (0)

    // 16 MFMA: quadrant MQ x all 4 j, one k-half
#define MMA16(MQ, AA, BB) do {                                                  \
        _Pragma("unroll") for (int i_ = 0; i_ < 4; ++i_)                        \
        _Pragma("unroll") for (int j_ = 0; j_ < 4; ++j_)                        \
            acc[(MQ) * 4 + i_][j_] =                                            \
                __builtin_amdgcn_mfma_f32_16x16x32_bf16(                        \
                    AA[i_], BB[j_], acc[(MQ) * 4 + i_][j_], 0, 0, 0);           \
    } while (0)

    // ---- prologue: stage tile 0 -> buf0 (8 loads); loop top drains it ----
    STAGE(Xb, rbase, 0, 0, 0, 0);
    STAGE(Xb, rbase, 0, 0, 0, 1);
    STAGE(Wb, nbase, 0, 0, 1, 0);
    STAGE(Wb, nbase, 0, 0, 1, 1);

    // ---- main loop: 1 barrier + 1 vmcnt per K-tile, free-form body ----
#define KBODY(TT, BUF) do {                                                     \
        const int kt1_ = ((TT) + 1) & (NKT - 1);                                \
        ASM_VMCNT0;          /* own stage(TT) landed */                         \
        SBAR;                /* all waves' stage(TT) landed; reads(TT-1) done */\
        SFENCE;              /* keep reads below the barrier */                 \
        STAGE(Xb, rbase, kt1_, (BUF) ^ 1, 0, 0);                                \
        STAGE(Xb, rbase, kt1_, (BUF) ^ 1, 0, 1);                                \
        STAGE(Wb, nbase, kt1_, (BUF) ^ 1, 1, 0);                                \
        STAGE(Wb, nbase, kt1_, (BUF) ^ 1, 1, 1);                                \
        LOAD_B4(bk0, BUF, 0);                                                   \
        LOAD_B4(bk1, BUF, 1);                                                   \
        LOAD_A4(a0, BUF, 0, 0);                                                 \
        LOAD_A4(a1, BUF, 0, 1);                                                 \
        MMA16(0, a0, bk0);                                                      \
        MMA16(0, a1, bk1);                                                      \
        LOAD_A4(a0, BUF, 1, 0);                                                 \
        LOAD_A4(a1, BUF, 1, 1);                                                 \
        MMA16(1, a0, bk0);                                                      \
        MMA16(1, a1, bk1);                                                      \
    } while (0)

    for (int t = 0; t < NKT; t += 2) {
        KBODY(t, 0);
        KBODY(t + 1, 1);
    }

    // ---- fused LSTM epilogue (reg-resident, zero-shuffle) ----
    const int s = (nblk * 4 + wn) * 16 + l15;
    float bg[4];
    #pragma unroll
    for (int jj = 0; jj < 4; ++jj)
        bg[jj] = biasR[nbase + wn * 64 + jj * 16 + l15];

    #pragma unroll
    for (int mi = 0; mi < 8; ++mi) {
        #pragma unroll
        for (int r = 0; r < 4; ++r) {
            const int row = rbase + wm * 128 + mi * 16 + krow * 4 + r;
            float fg = sigm(acc[mi][0][r] + bg[0]);
            float ig = sigm(acc[mi][1][r] + bg[1]);
            float og = sigm(acc[mi][2][r] + bg[2]);
            float gg = tanh_fast(acc[mi][3][r] + bg[3]);
            float oc = old_cell[(size_t)row * SD + s];
            float nc = fmaf(fg, oc, ig * gg);
            float nh = og * tanh_fast(nc);
            new_h[(size_t)row * SD + s]    = nh;
            new_cell[(size_t)row * SD + s] = nc;
        }
    }
}

extern "C" void kernel_launch(void* const* d_in, const int* in_sizes, int n_in,
                              void* d_out, int out_size, void* d_ws, size_t ws_size,
                              hipStream_t stream) {
    const float* input    = (const float*)d_in[0];
    const float* old_h    = (const float*)d_in[1];
    const float* old_cell = (const float*)d_in[2];
    const float* weights  = (const float*)d_in[3];
    const float* bias     = (const float*)d_in[4];

    unsigned short* Xb  = (unsigned short*)d_ws;                             // 16 MiB
    unsigned short* Wb  = (unsigned short*)((char*)d_ws + (size_t)16777216); // 16 MiB
    float*          bR  = (float*)((char*)d_ws + (size_t)33554432);          // 16 KiB

    float* out_h = (float*)d_out;
    float* out_c = out_h + (size_t)NB * SD;

    pack_kernel<<<2048, 256, 0, stream>>>(input, old_h, weights, bias, Xb, Wb, bR);
    lstm_gemm<<<(NB / BM) * (ND / BN), 512, 0, stream>>>(Xb, Wb, bR, old_cell,
                                                         out_h, out_c);
}